// Round 2
// baseline (1985.253 us; speedup 1.0000x reference)
//
#include <hip/hip_runtime.h>

#define RES 64
#define CHANNEL 32
#define DIM 512
#define BATCH 32
#define ROWS (RES * RES * CHANNEL)   // 131072

#define BM 128        // rows per block tile
#define BK 32         // k-chunk
#define TM 2          // rows per thread
#define TN 8          // batch cols per thread
#define NCHUNK (DIM / BK)  // 16

// Kernel 1: scaledT[d][b] = L[d] * style[b][d]   (512 x 32 floats = 64 KiB in d_ws)
__global__ void scale_kernel(const float* __restrict__ style,
                             const float* __restrict__ L,
                             float* __restrict__ scaledT) {
    int i = blockIdx.x * 256 + threadIdx.x;   // 0 .. 16383
    int d = i >> 5;
    int b = i & 31;
    scaledT[d * 32 + b] = L[d] * style[b * DIM + d];
}

// Kernel 2: out[b*ROWS + m] = sum_d U[m*DIM+d] * scaledT[d*32+b] + mu[m]
__global__ __launch_bounds__(256, 4) void eigen_kernel(
    const float* __restrict__ U,
    const float* __restrict__ mu,
    const float* __restrict__ scaledT,
    float* __restrict__ out) {

    // Double-buffered U tile (XOR-swizzled) + scaled tile. 2*(16+4) = 40 KiB -> 4 blocks/CU.
    __shared__ __align__(16) float Ut[2][BM * BK];     // 2 x 16 KiB
    __shared__ __align__(16) float Sc[2][BK * BATCH];  // 2 x 4 KiB, layout [d][b]

    const int tid = threadIdx.x;
    const int l  = tid & 63;                 // lane (0..63)
    const int cg = tid >> 6;                 // wave id (0..3) -> batch col group
    const int b0 = __builtin_amdgcn_readfirstlane(cg * TN);
    const int sw = (l & 7) * 4;              // XOR bank swizzle for this lane's rows
    const int R0 = blockIdx.x * BM;

    float acc[TM][TN];
#pragma unroll
    for (int r = 0; r < TM; ++r)
#pragma unroll
        for (int b = 0; b < TN; ++b) acc[r][b] = 0.0f;

    // ---- staging geometry ----
    // U tile: 128 rows x 8 float4/row = 1024 float4; 4 per thread.
    //   piece j: f = j*256 + tid; row = j*32 + (tid>>3); dd = (tid&7)*4
    const int srow_base = tid >> 3;          // + j*32
    const int sdd       = (tid & 7) * 4;
    const int lds_sw    = sdd ^ (((tid >> 3) & 7) * 4);   // row&7 == (tid>>3)&7
    // Sc tile: 32 d x 32 b = 256 float4; 1 per thread. d = tid>>3, b4 = (tid&7)*4
    const float4* sg4 = (const float4*)scaledT;           // global scaledT as float4

    float4 pre[4];
    float4 spre;

    // prologue: load + store chunk 0
#pragma unroll
    for (int j = 0; j < 4; ++j) {
        int row = srow_base + j * 32;
        pre[j] = *(const float4*)&U[(size_t)(R0 + row) * DIM + sdd];
    }
    spre = sg4[tid];   // chunk 0: scaledT float4 index c*256 + tid
#pragma unroll
    for (int j = 0; j < 4; ++j) {
        int row = srow_base + j * 32;
        *(float4*)&Ut[0][row * BK + lds_sw] = pre[j];
    }
    *(float4*)&Sc[0][tid * 4] = spre;        // position d*32+b4 == tid*4
    __syncthreads();

#pragma unroll 1
    for (int c = 0; c < NCHUNK; ++c) {
        const int cur = c & 1;

        // issue global prefetch of chunk c+1
        if (c + 1 < NCHUNK) {
#pragma unroll
            for (int j = 0; j < 4; ++j) {
                int row = srow_base + j * 32;
                pre[j] = *(const float4*)&U[(size_t)(R0 + row) * DIM + (c + 1) * BK + sdd];
            }
            spre = sg4[(c + 1) * 256 + tid];
        }

        const float* ut = &Ut[cur][0];
        const float4* sc4 = (const float4*)&Sc[cur][0];

#pragma unroll
        for (int dd = 0; dd < BK; dd += 4) {
            float4 u[TM];
#pragma unroll
            for (int r = 0; r < TM; ++r) {
                int tr = l + 64 * r;
                u[r] = *(const float4*)&ut[tr * BK + (dd ^ sw)];
            }
#pragma unroll
            for (int j = 0; j < 4; ++j) {
                // wave-uniform LDS reads -> broadcast, conflict-free
                float4 sA = sc4[(dd + j) * 8 + (b0 >> 2)];
                float4 sB = sc4[(dd + j) * 8 + (b0 >> 2) + 1];
#pragma unroll
                for (int r = 0; r < TM; ++r) {
                    float uv = (j == 0) ? u[r].x : (j == 1) ? u[r].y : (j == 2) ? u[r].z : u[r].w;
                    acc[r][0] += uv * sA.x;
                    acc[r][1] += uv * sA.y;
                    acc[r][2] += uv * sA.z;
                    acc[r][3] += uv * sA.w;
                    acc[r][4] += uv * sB.x;
                    acc[r][5] += uv * sB.y;
                    acc[r][6] += uv * sB.z;
                    acc[r][7] += uv * sB.w;
                }
            }
        }

        // write prefetched chunk into the other buffer
        if (c + 1 < NCHUNK) {
#pragma unroll
            for (int j = 0; j < 4; ++j) {
                int row = srow_base + j * 32;
                *(float4*)&Ut[cur ^ 1][row * BK + lds_sw] = pre[j];
            }
            *(float4*)&Sc[cur ^ 1][tid * 4] = spre;
        }
        __syncthreads();
    }

    // epilogue: out[b][m] = acc + mu[m]
#pragma unroll
    for (int r = 0; r < TM; ++r) {
        int m = R0 + l + 64 * r;
        float muv = mu[m];
#pragma unroll
        for (int bb = 0; bb < TN; ++bb) {
            out[(size_t)(b0 + bb) * ROWS + m] = acc[r][bb] + muv;
        }
    }
}

extern "C" void kernel_launch(void* const* d_in, const int* in_sizes, int n_in,
                              void* d_out, int out_size, void* d_ws, size_t ws_size,
                              hipStream_t stream) {
    const float* style = (const float*)d_in[0];   // [32, 512]
    const float* U     = (const float*)d_in[1];   // [64, 64, 32, 512]
    const float* L     = (const float*)d_in[2];   // [512]
    const float* mu    = (const float*)d_in[3];   // [64, 64, 32]
    float* out = (float*)d_out;                   // [32, 64, 64, 32]
    float* scaledT = (float*)d_ws;                // 512*32 floats = 64 KiB

    scale_kernel<<<64, 256, 0, stream>>>(style, L, scaledT);
    eigen_kernel<<<ROWS / BM, 256, 0, stream>>>(U, mu, scaledT, out);
}

// Round 3
// 386.975 us; speedup vs baseline: 5.1302x; 5.1302x over previous
//
#include <hip/hip_runtime.h>

#define RES 64
#define CHANNEL 32
#define DIM 512
#define BATCH 32
#define ROWS (RES * RES * CHANNEL)   // 131072

// Kernel 1: scaledT[d*32+b] = L[d] * style[b][d]   (512 x 32 floats = 64 KiB in d_ws)
__global__ void scale_kernel(const float* __restrict__ style,
                             const float* __restrict__ L,
                             float* __restrict__ scaledT) {
    int i = blockIdx.x * 256 + threadIdx.x;   // 0 .. 16383
    int d = i >> 5;
    int b = i & 31;
    scaledT[i] = L[d] * style[b * DIM + d];
}

// Kernel 2: one thread per output row m. acc[b] = sum_d U[m,d]*scaled[d][b]; out[b][m] = acc[b]+mu[m].
// U has no cross-row reuse -> no LDS staging of U at all. Only `scaled` is shared: staged in LDS once.
__global__ __launch_bounds__(256, 2) void eigen_kernel(
    const float* __restrict__ U,
    const float* __restrict__ mu,
    const float* __restrict__ scaledT,
    float* __restrict__ out) {

    __shared__ __align__(16) float Sc[DIM * BATCH];  // 64 KiB -> 2 blocks/CU

    const int tid = threadIdx.x;

    // stage all of scaled into LDS (coalesced, 16 float4 per thread), ONE barrier total
    {
        const float4* g = (const float4*)scaledT;
        float4* s = (float4*)Sc;
#pragma unroll
        for (int j = 0; j < 16; ++j)
            s[j * 256 + tid] = g[j * 256 + tid];
    }
    __syncthreads();

    const size_t row = (size_t)blockIdx.x * 256 + tid;
    const float4* __restrict__ u4 = (const float4*)(U + row * DIM);
    const float4* __restrict__ sc4 = (const float4*)Sc;

    float acc[BATCH];
#pragma unroll
    for (int b = 0; b < BATCH; ++b) acc[b] = 0.0f;

    // body = 16 d's = 4 float4 per lane = exactly one 64B line per lane.
    // Prefetch next body's line while computing 512 FMAs on the current one.
    float4 cur[4], nxt[4];
#pragma unroll
    for (int p = 0; p < 4; ++p) cur[p] = u4[p];

#pragma unroll 1
    for (int body = 0; body < DIM / 16; ++body) {   // 32 bodies
        if (body + 1 < DIM / 16) {
#pragma unroll
            for (int p = 0; p < 4; ++p) nxt[p] = u4[(body + 1) * 4 + p];
        }
#pragma unroll
        for (int p = 0; p < 4; ++p) {
            const int dbase = body * 16 + p * 4;
#pragma unroll
            for (int j = 0; j < 4; ++j) {
                const float uj = (j == 0) ? cur[p].x : (j == 1) ? cur[p].y
                               : (j == 2) ? cur[p].z : cur[p].w;
                const int sbase = (dbase + j) * 8;   // float4 index of Sc row d
#pragma unroll
                for (int q = 0; q < 8; ++q) {
                    // wave-uniform address -> broadcast, conflict-free
                    float4 s = sc4[sbase + q];
                    acc[q * 4 + 0] += uj * s.x;
                    acc[q * 4 + 1] += uj * s.y;
                    acc[q * 4 + 2] += uj * s.z;
                    acc[q * 4 + 3] += uj * s.w;
                }
            }
        }
#pragma unroll
        for (int p = 0; p < 4; ++p) cur[p] = nxt[p];
    }

    const float muv = mu[row];
#pragma unroll
    for (int b = 0; b < BATCH; ++b)
        out[(size_t)b * ROWS + row] = acc[b] + muv;   // per wave: 256B contiguous per b
}

extern "C" void kernel_launch(void* const* d_in, const int* in_sizes, int n_in,
                              void* d_out, int out_size, void* d_ws, size_t ws_size,
                              hipStream_t stream) {
    const float* style = (const float*)d_in[0];   // [32, 512]
    const float* U     = (const float*)d_in[1];   // [64, 64, 32, 512]
    const float* L     = (const float*)d_in[2];   // [512]
    const float* mu    = (const float*)d_in[3];   // [64, 64, 32]
    float* out = (float*)d_out;                   // [32, 64, 64, 32]
    float* scaledT = (float*)d_ws;                // 512*32 floats = 64 KiB

    scale_kernel<<<64, 256, 0, stream>>>(style, L, scaledT);
    eigen_kernel<<<ROWS / 256, 256, 0, stream>>>(U, mu, scaledT, out);
}